// Round 7
// baseline (229.891 us; speedup 1.0000x reference)
//
#include <hip/hip_runtime.h>
#include <math.h>

typedef float f4 __attribute__((ext_vector_type(4)));

static __device__ __forceinline__ void stnt(float* p, f4 v) {
    __builtin_nontemporal_store(v, (f4*)p);
}

// x: [B=4][A=64][S=64][C=64][F=64] fp32.
// out = x * att_c[b,c,f] * att_s[b,s,f] * att_a[b,a,f]
//
// Single persistent kernel, 4 phases separated by a manual device-scope
// grid barrier (hipLaunchCooperativeKernel failed to launch in this harness
// in R6 -> manual barrier + plain launch; grid sized from the occupancy
// query so all blocks are co-resident; all phases grid-stride).

static __device__ __forceinline__ void gbar(unsigned* cnt, unsigned* rel,
                                            unsigned nblk, unsigned phase) {
    __syncthreads();
    if (threadIdx.x == 0) {
        __threadfence();   // agent release: writes visible device-wide (L2 wb)
        unsigned prev = __hip_atomic_fetch_add(cnt, 1u, __ATOMIC_ACQ_REL,
                                               __HIP_MEMORY_SCOPE_AGENT);
        if (prev == nblk * phase - 1u) {
            __hip_atomic_store(rel, phase, __ATOMIC_RELEASE,
                               __HIP_MEMORY_SCOPE_AGENT);
        } else {
            while (__hip_atomic_load(rel, __ATOMIC_ACQUIRE,
                                     __HIP_MEMORY_SCOPE_AGENT) < phase)
                __builtin_amdgcn_s_sleep(2);
        }
        __threadfence();   // agent acquire: invalidate stale L1/L2
    }
    __syncthreads();
}

__global__ __launch_bounds__(256) void fused_kernel(
    const float* __restrict__ x,
    const float* __restrict__ w1_a, const float* __restrict__ w1_s, const float* __restrict__ w1_c,
    const float* __restrict__ w2_a, const float* __restrict__ w2_s, const float* __restrict__ w2_c,
    float* __restrict__ out,
    float* __restrict__ ps, float* __restrict__ pc,
    float* __restrict__ m_a, float* __restrict__ m_s, float* __restrict__ m_c,
    float* __restrict__ att_a, float* __restrict__ att_s, float* __restrict__ att_c,
    unsigned* __restrict__ bar)
{
    __shared__ float shl[8192];           // 32 KiB, re-purposed per phase
    const int t = threadIdx.x;
    const unsigned nblk = gridDim.x;
    unsigned* cnt = bar;
    unsigned* rel = bar + 32;             // separate 128-B line

    // ---------------- phase 1: pool ----------------
    {
        const int w = t >> 6, lane = t & 63;
        const int fg = lane & 15;         // f = fg*4
        const int cq = lane >> 4;         // c-quarter
        float (*lds)[4096] = (float(*)[4096])shl;

        for (unsigned vb = blockIdx.x; vb < 1024; vb += nblk) {
            const int q = vb & 3, ba = vb >> 2;
            const float* xa = x + (size_t)ba * 262144;

            f4 csum[16];
#pragma unroll
            for (int j = 0; j < 16; ++j) csum[j] = f4{0.f, 0.f, 0.f, 0.f};

#pragma unroll
            for (int r = 0; r < 4; ++r) {
                const int s = q * 16 + w * 4 + r;
                const float* xs = xa + s * 4096 + cq * 1024 + fg * 4;
                f4 ssum = f4{0.f, 0.f, 0.f, 0.f};
#pragma unroll
                for (int j = 0; j < 16; ++j) {
                    f4 v = *(const f4*)(xs + j * 64);
                    ssum += v;
                    csum[j] += v;
                }
#pragma unroll
                for (int i = 0; i < 4; ++i) ssum[i] += __shfl_xor(ssum[i], 16);
#pragma unroll
                for (int i = 0; i < 4; ++i) ssum[i] += __shfl_xor(ssum[i], 32);
                if (cq == 0)
                    *(f4*)(ps + (size_t)ba * 4096 + s * 64 + fg * 4) = ssum;
            }

            __syncthreads();              // protect lds across vb iterations
            if (w >= 2) {
#pragma unroll
                for (int j = 0; j < 16; ++j)
                    *(f4*)(&lds[w - 2][(cq * 16 + j) * 64 + fg * 4]) = csum[j];
            }
            __syncthreads();
            if (w < 2) {
#pragma unroll
                for (int j = 0; j < 16; ++j)
                    csum[j] += *(const f4*)(&lds[w][(cq * 16 + j) * 64 + fg * 4]);
            }
            __syncthreads();
            if (w == 1) {
#pragma unroll
                for (int j = 0; j < 16; ++j)
                    *(f4*)(&lds[0][(cq * 16 + j) * 64 + fg * 4]) = csum[j];
            }
            __syncthreads();
            if (w == 0) {
                float* dst = pc + (size_t)vb * 4096;
#pragma unroll
                for (int j = 0; j < 16; ++j) {
                    f4 o = *(const f4*)(&lds[0][(cq * 16 + j) * 64 + fg * 4]);
                    *(f4*)(dst + (cq * 16 + j) * 64 + fg * 4) = csum[j] + o;
                }
            }
        }
    }
    gbar(cnt, rel, nblk, 1);

    // ---------------- phase 2: reduce ----------------
    {
        const int g = t >> 6, f = t & 63;
        float (*sm)[64] = (float(*)[64])shl;
        for (unsigned vb = blockIdx.x; vb < 768; vb += nblk) {
            const int region = vb >> 8;
            const int b = (vb >> 6) & 3;
            const int d = vb & 63;
            float acc = 0.f;
            if (region == 0) {
#pragma unroll 8
                for (int i = g; i < 256; i += 4)
                    acc += pc[(size_t)(b * 256 + i) * 4096 + d * 64 + f];
            } else if (region == 1) {
#pragma unroll 8
                for (int i = g; i < 64; i += 4)          // m_s: sum over a
                    acc += ps[((size_t)(b * 64 + i) * 64 + d) * 64 + f];
            } else {
#pragma unroll 8
                for (int i = g; i < 64; i += 4)          // m_a: sum over s
                    acc += ps[((size_t)(b * 64 + d) * 64 + i) * 64 + f];
            }
            __syncthreads();
            sm[g][f] = acc;
            __syncthreads();
            if (t < 64) {
                float tot = (sm[0][t] + sm[1][t] + sm[2][t] + sm[3][t]) * (1.f / 4096.f);
                float* dst = region == 0 ? m_c : (region == 1 ? m_s : m_a);
                dst[((size_t)b * 64 + d) * 64 + t] = tot;
            }
        }
    }
    gbar(cnt, rel, nblk, 2);

    // ---------------- phase 3: attn ----------------
    {
        float* w1ld = shl;                 // 1024
        float* w2ld = shl + 1024;          // 1024
        float (*mld)[64] = (float(*)[64])(shl + 2048);   // 4*64
        float (*zld)[16] = (float(*)[16])(shl + 2304);   // 4*16
        for (unsigned vb = blockIdx.x; vb < 192; vb += nblk) {
            const int axis = vb >> 6;
            const int f    = vb & 63;
            const float* m  = axis == 0 ? m_a  : (axis == 1 ? m_s  : m_c);
            const float* w1 = axis == 0 ? w1_a : (axis == 1 ? w1_s : w1_c);
            const float* w2 = axis == 0 ? w2_a : (axis == 1 ? w2_s : w2_c);
            float* att      = axis == 0 ? att_a : (axis == 1 ? att_s : att_c);

            __syncthreads();
            if (t < 64) {
                const f4* s1 = (const f4*)(w1 + (size_t)f * 1024);
                const f4* s2 = (const f4*)(w2 + (size_t)f * 1024);
#pragma unroll
                for (int i = 0; i < 4; ++i) {
                    ((f4*)w1ld)[t + 64 * i] = s1[t + 64 * i];
                    ((f4*)w2ld)[t + 64 * i] = s2[t + 64 * i];
                }
#pragma unroll
                for (int bb = 0; bb < 4; ++bb)
                    mld[bb][t] = m[((size_t)bb * 64 + t) * 64 + f];
            }
            __syncthreads();
            if (t < 64) {
                const int bb = t >> 4, e = t & 15;
                float acc = 0.f;
#pragma unroll
                for (int dd = 0; dd < 64; ++dd) acc += mld[bb][dd] * w1ld[dd * 16 + e];
                zld[bb][e] = fmaxf(acc, 0.f);
            }
            __syncthreads();
            if (t < 64) {
#pragma unroll
                for (int bb = 0; bb < 4; ++bb) {
                    float acc = 0.f;
#pragma unroll
                    for (int e = 0; e < 16; ++e) acc += zld[bb][e] * w2ld[e * 64 + t];
                    att[((size_t)bb * 64 + t) * 64 + f] = 1.f / (1.f + expf(-acc));
                }
            }
        }
    }
    gbar(cnt, rel, nblk, 3);

    // ---------------- phase 4: scale ----------------
    {
        const int fg = t & 15;
        const int cq = t >> 4;
        float (*acl)[68] = (float(*)[68])shl;            // 64*68 = 4352
        float (*asl)[64] = (float(*)[64])(shl + 4352);   // 8*64  = 512

        for (unsigned u = blockIdx.x; u < 2048; u += nblk) {
            const int blk2 = 2047 - (int)u;   // b=3 first: tail of pool's stream
            const int so = blk2 & 7;
            const int a  = (blk2 >> 3) & 63;
            const int b  = blk2 >> 9;

            __syncthreads();
            {
                const f4* srcc = (const f4*)(att_c + (size_t)b * 4096);
#pragma unroll
                for (int i = 0; i < 4; ++i) {
                    int qq = t + 256 * i;          // f4 id: c = qq>>4, f = (qq&15)*4
                    f4 v = srcc[qq];
                    *(f4*)(&acl[qq >> 4][(qq & 15) * 4]) = v;
                }
                if (t < 128) {
                    f4 v = *(const f4*)(att_s + (size_t)b * 4096 + so * 512 + t * 4);
                    *(f4*)(&asl[t >> 4][(t & 15) * 4]) = v;
                }
            }
            f4 aa = *(const f4*)(att_a + (size_t)b * 4096 + a * 64 + fg * 4);
            __syncthreads();

            f4 acv[4];
#pragma unroll
            for (int k = 0; k < 4; ++k)
                acv[k] = *(const f4*)(&acl[k * 16 + cq][fg * 4]);

            const size_t base = (size_t)(b * 4096 + a * 64 + so * 8) * 4096;
            const float* xs = x + base;
            float* os = out + base;

            for (int sl = 0; sl < 8; ++sl) {
                f4 m0 = aa * *(const f4*)(&asl[sl][fg * 4]);
#pragma unroll
                for (int k = 0; k < 4; ++k) {
                    const int c = k * 16 + cq;
                    const size_t off = (size_t)(sl * 64 + c) * 64 + fg * 4;
                    f4 v = *(const f4*)(xs + off);
                    stnt(os + off, v * m0 * acv[k]);
                }
            }
        }
    }
}

extern "C" void kernel_launch(void* const* d_in, const int* in_sizes, int n_in,
                              void* d_out, int out_size, void* d_ws, size_t ws_size,
                              hipStream_t stream)
{
    (void)in_sizes; (void)n_in; (void)out_size; (void)ws_size;
    const float* x    = (const float*)d_in[0];
    const float* w1_a = (const float*)d_in[1];
    const float* w1_s = (const float*)d_in[2];
    const float* w1_c = (const float*)d_in[3];
    const float* w2_a = (const float*)d_in[4];
    const float* w2_s = (const float*)d_in[5];
    const float* w2_c = (const float*)d_in[6];
    float* out = (float*)d_out;

    // Workspace layout (fully rewritten each call before being read):
    float* ps    = (float*)d_ws;            // [4][64][64][64]   4 MiB
    float* pc    = ps + 1048576;            // [1024][64][64]   16 MiB
    float* m_a   = pc + 4194304;            // [4][64][64]      64 KiB each
    float* m_s   = m_a + 16384;
    float* m_c   = m_s + 16384;
    float* att_a = m_c + 16384;
    float* att_s = att_a + 16384;
    float* att_c = att_s + 16384;
    unsigned* bar = (unsigned*)(att_c + 16384);   // 2 words, 128-B apart

    // Zero barrier state every call (async, capture-safe).
    hipMemsetAsync((void*)bar, 0, 256, stream);

    // Co-residency-safe grid size (host-only query).
    int maxBlocksPerCU = 0;
    hipError_t e = hipOccupancyMaxActiveBlocksPerMultiprocessor(
        &maxBlocksPerCU, fused_kernel, 256, 0);
    int grid;
    if (e != hipSuccess || maxBlocksPerCU < 1) {
        grid = 256;                         // 1 block/CU: trivially co-resident
    } else {
        grid = maxBlocksPerCU * 256;        // 256 CUs on MI355X
        if (grid > 1024) grid = 1024;
    }

    hipLaunchKernelGGL(fused_kernel, dim3(grid), dim3(256), 0, stream,
                       x, w1_a, w1_s, w1_c, w2_a, w2_s, w2_c, out,
                       ps, pc, m_a, m_s, m_c, att_a, att_s, att_c, bar);
}